// Round 2
// baseline (38515.112 us; speedup 1.0000x reference)
//
#include <hip/hip_runtime.h>

// Decoder: 2-layer LSTM (H=256), T=512, B=256, scalar feedback.
// Round 2: model-sliced persistent kernel. 8 groups x 32 blocks; each block
// owns 8 h-rows (32 gate rows, 96 KB weights streamed from L2 per step) for a
// 32-batch window. h0/h1 exchanged via double-buffered global arena; two
// custom device-scope group barriers per step (monotonic counter).

namespace {

constexpr int kB = 256, kT = 512, kH = 256;
constexpr int kSGrp = 32;   // blocks per group
constexpr int kMGrp = 32;   // batch per group
constexpr int kHRows = 8;   // h-rows per block

// ws layout (float indices)
constexpr int kH0Off = 0;              // h0buf[2][256][256]
constexpr int kH1Off = 131072;         // h1buf[2][256][256]
constexpr int kPredOff = 262144;       // predbuf[2][256]
constexpr int kCntOff = 262656;        // int counters (zeroed per launch)
constexpr size_t kWsBytesNeeded = (kCntOff + 64) * sizeof(float);

__device__ __forceinline__ float fsig(float v) { return 1.0f / (1.0f + __expf(-v)); }

__device__ __forceinline__ void group_barrier(int* cnt, int target) {
  __syncthreads();  // all block threads done with prior phase
  if (threadIdx.x == 0) {
    __hip_atomic_fetch_add(cnt, 1, __ATOMIC_RELEASE, __HIP_MEMORY_SCOPE_AGENT);
    while (__hip_atomic_load(cnt, __ATOMIC_RELAXED, __HIP_MEMORY_SCOPE_AGENT) < target) {
      __builtin_amdgcn_s_sleep(2);
    }
    (void)__hip_atomic_load(cnt, __ATOMIC_ACQUIRE, __HIP_MEMORY_SCOPE_AGENT);
  }
  __syncthreads();
}

__global__ __launch_bounds__(1024) void decoder_sliced(
    const float* __restrict__ seq, const float* __restrict__ z,
    const float* __restrict__ wih0, const float* __restrict__ bih0,
    const float* __restrict__ bhh0, const float* __restrict__ whh0,
    const float* __restrict__ wih1, const float* __restrict__ whh1,
    const float* __restrict__ bih1, const float* __restrict__ bhh1,
    const float* __restrict__ wout, const float* __restrict__ bout,
    float* __restrict__ ws, float* __restrict__ loss_out) {
  __shared__ float sg[32 * 33];     // gate accs [r][m], r = q*8+s
  __shared__ float spred[8 * 33];   // pred partials [hr][m]

  float* h0buf = ws + kH0Off;
  float* h1buf = ws + kH1Off;
  float* predbuf = ws + kPredOff;
  int* cnt_all = (int*)(ws + kCntOff);

  const int tid = threadIdx.x;
  const int g = blockIdx.x >> 5;   // group 0..7
  const int j = blockIdx.x & 31;   // block in group
  const int m0 = g * kMGrp;        // batch window base
  const int hr0 = j * kHRows;      // global h-row base of this block's slice
  int* cnt = cnt_all + g;

  const int r = tid >> 5;  // local gate row 0..31
  const int m = tid & 31;  // local batch 0..31
  const int q = r >> 3;    // gate quadrant (i,f,g,o)
  const int s = r & 7;     // h-row within slice
  const int grow = q * kH + hr0 + s;  // global gate row in [0,1024)

  const float wih0_r = wih0[grow];
  const float bias0 = bih0[grow] + bhh0[grow];
  const float bias1 = bih1[grow] + bhh1[grow];
  const float4* w0row = (const float4*)(whh0 + (size_t)grow * kH);
  const float4* wi1row = (const float4*)(wih1 + (size_t)grow * kH);
  const float4* wh1row = (const float4*)(whh1 + (size_t)grow * kH);
  const float bo = bout[0];

  // cell-state owners: threads 0..255 hold c0,c1 for (hr = tid>>5, mm = tid&31)
  const int hr = tid >> 5;  // 0..7 when tid<256
  const int mm = tid & 31;
  float c0 = 0.f, c1 = 0.f, wout_r = 0.f;
  if (tid < 256) {
    float zv = z[(size_t)(m0 + mm) * kH + (hr0 + hr)];
    c0 = zv;
    c1 = zv;
    wout_r = wout[hr0 + hr];
  }

  // init: fill parity-0 h buffers (group fills its own m-window; block j owns
  // k-rows [8j, 8j+8)) and zero the group's pred windows.
  if (tid < 256) {
    int kk = j * kHRows + (tid >> 5);
    float v = z[(size_t)(m0 + mm) * kH + kk];
    h0buf[kk * kB + m0 + mm] = v;
    h1buf[kk * kB + m0 + mm] = v;
  }
  if (j == 1 && tid < 32) {
    predbuf[m0 + tid] = 0.f;
    predbuf[kB + m0 + tid] = 0.f;
  }

  int target = kSGrp;
  group_barrier(cnt, target);

  float lacc = 0.f;
  for (int t = 0; t < kT; ++t) {
    const int p = t & 1;
    float* h0r = h0buf + p * 65536;
    float* h0w = h0buf + (1 - p) * 65536;
    float* h1r = h1buf + p * 65536;
    float* h1w = h1buf + (1 - p) * 65536;
    float* predr = predbuf + p * kB;
    float* predw = predbuf + (1 - p) * kB;

    // loss for pred(t-1) (consumer side, after barrier B of t-1)
    if (j == 0 && tid < 32 && t > 0) {
      float d = seq[(size_t)(m0 + tid) * kT + (t - 1)] - predr[m0 + tid];
      lacc = fmaf(d, d, lacc);
    }
    // zero next pred accumulator window (published by barrier A)
    if (j == 1 && tid < 32) predw[m0 + tid] = 0.f;

    // ---- phase 1: gates0[grow][m] = x*wih0 + b + dot(Whh0[grow,:], h0) ----
    float x = predr[m0 + m];
    float a = fmaf(x, wih0_r, bias0);
    {
      const float* hp0 = h0r + m0 + m;
#pragma unroll 4
      for (int k4 = 0; k4 < 64; ++k4) {
        float4 w = w0row[k4];
        const float* h = hp0 + (k4 << 10);
        a = fmaf(w.x, h[0], a);
        a = fmaf(w.y, h[256], a);
        a = fmaf(w.z, h[512], a);
        a = fmaf(w.w, h[768], a);
      }
    }
    sg[r * 33 + m] = a;
    __syncthreads();
    if (tid < 256) {
      float gi = fsig(sg[(0 + hr) * 33 + mm]);
      float gf = fsig(sg[(8 + hr) * 33 + mm]);
      float gg = tanhf(sg[(16 + hr) * 33 + mm]);
      float go = fsig(sg[(24 + hr) * 33 + mm]);
      c0 = fmaf(gf, c0, gi * gg);
      float hn = go * tanhf(c0);
      h0w[(hr0 + hr) * kB + m0 + mm] = hn;  // publish h0(t) slice
    }
    target += kSGrp;
    group_barrier(cnt, target);  // barrier A: h0(t) + zeroed predw visible

    // ---- phase 2: gates1 = Wih1*h0new + b + Whh1*h1old ----
    a = bias1;
    {
      const float* hA = h0w + m0 + m;
      const float* hB = h1r + m0 + m;
#pragma unroll 2
      for (int k4 = 0; k4 < 64; ++k4) {
        float4 wA = wi1row[k4];
        const float* ha = hA + (k4 << 10);
        a = fmaf(wA.x, ha[0], a);
        a = fmaf(wA.y, ha[256], a);
        a = fmaf(wA.z, ha[512], a);
        a = fmaf(wA.w, ha[768], a);
        float4 wB = wh1row[k4];
        const float* hb = hB + (k4 << 10);
        a = fmaf(wB.x, hb[0], a);
        a = fmaf(wB.y, hb[256], a);
        a = fmaf(wB.z, hb[512], a);
        a = fmaf(wB.w, hb[768], a);
      }
    }
    sg[r * 33 + m] = a;
    __syncthreads();
    if (tid < 256) {
      float gi = fsig(sg[(0 + hr) * 33 + mm]);
      float gf = fsig(sg[(8 + hr) * 33 + mm]);
      float gg = tanhf(sg[(16 + hr) * 33 + mm]);
      float go = fsig(sg[(24 + hr) * 33 + mm]);
      c1 = fmaf(gf, c1, gi * gg);
      float hn = go * tanhf(c1);
      h1w[(hr0 + hr) * kB + m0 + mm] = hn;  // publish h1(t) slice
      spred[hr * 33 + mm] = hn * wout_r;
    }
    __syncthreads();
    if (tid < 32) {
      float sp = 0.f;
#pragma unroll
      for (int hh = 0; hh < 8; ++hh) sp += spred[hh * 33 + tid];
      if (j == 0) sp += bo;  // bias added exactly once per (m)
      atomicAdd(&predw[m0 + tid], sp);
    }
    target += kSGrp;
    group_barrier(cnt, target);  // barrier B: h1(t) + pred(t) visible
  }

  // final loss term: pred(T-1) lives in parity 0 (T even)
  if (j == 0 && tid < 32) {
    float d = seq[(size_t)(m0 + tid) * kT + (kT - 1)] - predbuf[m0 + tid];
    lacc = fmaf(d, d, lacc);
    atomicAdd(loss_out, lacc * (1.0f / (float)(kB * kT)));
  }
}

// ---------------- fallback (round-1 structure, no workspace needs) ----------
__global__ __launch_bounds__(1024) void decoder_fallback(
    const float* __restrict__ seq, const float* __restrict__ z,
    const float* __restrict__ wih0, const float* __restrict__ bih0,
    const float* __restrict__ bhh0, const float* __restrict__ whh0,
    const float* __restrict__ wih1, const float* __restrict__ whh1,
    const float* __restrict__ bih1, const float* __restrict__ bhh1,
    const float* __restrict__ wout, const float* __restrict__ bout,
    float* __restrict__ loss_out) {
  __shared__ float h0s[kH], h1s[kH], g4[1024];
  __shared__ float xs_s;
  const int tid = threadIdx.x;
  const int b = blockIdx.x;
  float c0r = 0.f, c1r = 0.f;
  if (tid < kH) {
    float zv = z[b * kH + tid];
    h0s[tid] = zv; h1s[tid] = zv; c0r = zv; c1r = zv;
  }
  if (tid == 0) xs_s = 0.f;
  const float wih0_j = wih0[tid];
  const float bias0_j = bih0[tid] + bhh0[tid];
  const float bias1_j = bih1[tid] + bhh1[tid];
  const float wout_r = (tid < kH) ? wout[tid] : 0.f;
  const float bo = bout[0];
  float lacc = 0.f;
  __syncthreads();
  for (int t = 0; t < kT; ++t) {
    float a0 = fmaf(xs_s, wih0_j, bias0_j);
    for (int k = 0; k < kH; ++k) a0 = fmaf(whh0[tid * kH + k], h0s[k], a0);
    g4[tid] = a0;
    __syncthreads();
    if (tid < kH) {
      float ig = fsig(g4[tid]), fg = fsig(g4[tid + 256]);
      float gg = tanhf(g4[tid + 512]), og = fsig(g4[tid + 768]);
      c0r = fmaf(fg, c0r, ig * gg);
      h0s[tid] = og * tanhf(c0r);
    }
    __syncthreads();
    float a1 = bias1_j;
    for (int k = 0; k < kH; ++k) a1 = fmaf(wih1[tid * kH + k], h0s[k], a1);
    for (int k = 0; k < kH; ++k) a1 = fmaf(whh1[tid * kH + k], h1s[k], a1);
    g4[tid] = a1;
    __syncthreads();
    if (tid < kH) {
      float ig = fsig(g4[tid]), fg = fsig(g4[tid + 256]);
      float gg = tanhf(g4[tid + 512]), og = fsig(g4[tid + 768]);
      c1r = fmaf(fg, c1r, ig * gg);
      float h1 = og * tanhf(c1r);
      h1s[tid] = h1;
      g4[tid] = h1 * wout_r;
    }
    __syncthreads();
    if (tid < 64) {
      float v = g4[tid] + g4[tid + 64] + g4[tid + 128] + g4[tid + 192];
#pragma unroll
      for (int off = 32; off > 0; off >>= 1) v += __shfl_down(v, off);
      if (tid == 0) {
        float pred = v + bo;
        float d = seq[b * kT + t] - pred;
        lacc = fmaf(d, d, lacc);
        xs_s = pred;
      }
    }
    __syncthreads();
  }
  if (tid == 0) atomicAdd(loss_out, lacc * (1.0f / (float)(kB * kT)));
}

}  // namespace

extern "C" void kernel_launch(void* const* d_in, const int* in_sizes, int n_in,
                              void* d_out, int out_size, void* d_ws, size_t ws_size,
                              hipStream_t stream) {
  const float* seq = (const float*)d_in[0];
  const float* z = (const float*)d_in[1];
  const float* wih0 = (const float*)d_in[3];
  const float* whh0 = (const float*)d_in[4];
  const float* bih0 = (const float*)d_in[5];
  const float* bhh0 = (const float*)d_in[6];
  const float* wih1 = (const float*)d_in[7];
  const float* whh1 = (const float*)d_in[8];
  const float* bih1 = (const float*)d_in[9];
  const float* bhh1 = (const float*)d_in[10];
  const float* wout = (const float*)d_in[11];
  const float* bout = (const float*)d_in[12];
  float* out = (float*)d_out;

  hipMemsetAsync(out, 0, sizeof(float), stream);

  if (ws_size >= kWsBytesNeeded) {
    // zero the barrier counters (monotonic per launch)
    hipMemsetAsync((char*)d_ws + (size_t)kCntOff * sizeof(float), 0,
                   64 * sizeof(int), stream);
    // 80 KB dynamic LDS forces 1 block/CU so all 256 blocks map 1:1 to CUs
    // (guarantees co-residency for spin barriers and no time-shared stragglers)
    decoder_sliced<<<256, 1024, 80 * 1024, stream>>>(
        seq, z, wih0, bih0, bhh0, whh0, wih1, whh1, bih1, bhh1, wout, bout,
        (float*)d_ws, out);
  } else {
    decoder_fallback<<<kB, 1024, 0, stream>>>(seq, z, wih0, bih0, bhh0, whh0,
                                              wih1, whh1, bih1, bhh1, wout, bout,
                                              out);
  }
}

// Round 3
// 12256.710 us; speedup vs baseline: 3.1424x; 3.1424x over previous
//
#include <hip/hip_runtime.h>
#include <hip/hip_fp16.h>

// Decoder: 2-layer LSTM (H=256), T=512, B=256, scalar output feedback.
// Round 3: zero-communication persistent blocks (round-1 structure), with
//  (a) fp16 weights repacked per launch into coalesced 16B tiles in d_ws,
//  (b) NB=2 batch elements per block (grid 128) to double arithmetic
//      intensity per weight byte streamed from L2.

namespace {

constexpr int kB = 256, kT = 512, kH = 256;
constexpr int kWinPerMat = 32;            // 256 k-values / 8 per window
constexpr int kMatElems = kWinPerMat * 1024;  // H8 tiles per matrix
constexpr size_t kWsNeeded = 3 * (size_t)kMatElems * 16;  // 1.5 MB

struct alignas(16) H8 { __half2 h[4]; };  // 8 fp16 weights

__device__ __forceinline__ float fsig(float v) { return 1.0f / (1.0f + __expf(-v)); }

// Repack fp32 (1024x256 row-major) -> fp16 tiles: dst[win*1024 + j] holds
// w[j][8win..8win+7]. Lane-consecutive j => coalesced 16B loads in main loop.
__global__ __launch_bounds__(256) void pack_w(const float* __restrict__ s0,
                                              const float* __restrict__ s1,
                                              const float* __restrict__ s2,
                                              H8* __restrict__ dst) {
  int idx = blockIdx.x * 256 + threadIdx.x;       // 0 .. 3*32768-1
  int mat = idx >> 15;                            // 0..2
  int loc = idx & 32767;                          // win*1024 + j
  int j = loc & 1023, win = loc >> 10;
  const float* src = (mat == 0 ? s0 : (mat == 1 ? s1 : s2)) + j * 256 + win * 8;
  H8 o;
#pragma unroll
  for (int i = 0; i < 4; ++i) o.h[i] = __floats2half2_rn(src[2 * i], src[2 * i + 1]);
  dst[idx] = o;
}

__global__ __launch_bounds__(1024) void decoder_nb2(
    const float* __restrict__ seq, const float* __restrict__ z,
    const float* __restrict__ wih0, const float* __restrict__ bih0,
    const float* __restrict__ bhh0, const float* __restrict__ bih1,
    const float* __restrict__ bhh1, const float* __restrict__ wout,
    const float* __restrict__ bout, const H8* __restrict__ w0,
    const H8* __restrict__ w1i, const H8* __restrict__ w1h,
    float* __restrict__ loss_out) {
  __shared__ alignas(16) float h0s[2][kH];
  __shared__ alignas(16) float h1s[2][kH];
  __shared__ float g4[2][1024];
  __shared__ float spred[2][kH];
  __shared__ float xs[2];

  const int tid = threadIdx.x;        // gate row j
  const int b0 = blockIdx.x * 2;      // batch pair
  const int m = tid >> 8, hr = tid & 255;  // cell-role (tid<512)

  float c0 = 0.f, c1 = 0.f, woutr = 0.f;
  if (tid < 512) {
    float zv = z[(size_t)(b0 + m) * kH + hr];
    h0s[m][hr] = zv;
    h1s[m][hr] = zv;
    c0 = zv;
    c1 = zv;
    woutr = wout[hr];
  }
  if (tid < 2) xs[tid] = 0.f;

  const float wih0_j = wih0[tid];
  const float bias0 = bih0[tid] + bhh0[tid];
  const float bias1 = bih1[tid] + bhh1[tid];
  const float bo = bout[0];
  float lacc = 0.f;
  __syncthreads();

  const H8* wp0 = w0 + tid;
  const H8* wpA = w1i + tid;
  const H8* wpB = w1h + tid;
  const float4* h0f0 = (const float4*)&h0s[0][0];
  const float4* h0f1 = (const float4*)&h0s[1][0];
  const float4* h1f0 = (const float4*)&h1s[0][0];
  const float4* h1f1 = (const float4*)&h1s[1][0];

  for (int t = 0; t < kT; ++t) {
    // ---- layer 0 gates for both batch elems ----
    float a0 = fmaf(xs[0], wih0_j, bias0);
    float a1 = fmaf(xs[1], wih0_j, bias0);
#pragma unroll 4
    for (int win = 0; win < kWinPerMat; ++win) {
      H8 wv = wp0[(size_t)win << 10];
      float4 pA = h0f0[2 * win], pB = h0f0[2 * win + 1];
      float4 qA = h0f1[2 * win], qB = h0f1[2 * win + 1];
      float2 f0 = __half22float2(wv.h[0]);
      float2 f1 = __half22float2(wv.h[1]);
      float2 f2 = __half22float2(wv.h[2]);
      float2 f3 = __half22float2(wv.h[3]);
      a0 = fmaf(f0.x, pA.x, a0); a0 = fmaf(f0.y, pA.y, a0);
      a0 = fmaf(f1.x, pA.z, a0); a0 = fmaf(f1.y, pA.w, a0);
      a0 = fmaf(f2.x, pB.x, a0); a0 = fmaf(f2.y, pB.y, a0);
      a0 = fmaf(f3.x, pB.z, a0); a0 = fmaf(f3.y, pB.w, a0);
      a1 = fmaf(f0.x, qA.x, a1); a1 = fmaf(f0.y, qA.y, a1);
      a1 = fmaf(f1.x, qA.z, a1); a1 = fmaf(f1.y, qA.w, a1);
      a1 = fmaf(f2.x, qB.x, a1); a1 = fmaf(f2.y, qB.y, a1);
      a1 = fmaf(f3.x, qB.z, a1); a1 = fmaf(f3.y, qB.w, a1);
    }
    g4[0][tid] = a0;
    g4[1][tid] = a1;
    __syncthreads();
    if (tid < 512) {
      float gi = fsig(g4[m][hr]);
      float gf = fsig(g4[m][hr + 256]);
      float gg = tanhf(g4[m][hr + 512]);
      float go = fsig(g4[m][hr + 768]);
      c0 = fmaf(gf, c0, gi * gg);
      h0s[m][hr] = go * tanhf(c0);
    }
    __syncthreads();

    // ---- layer 1 gates: Wih1 @ h0new + Whh1 @ h1old ----
    a0 = bias1;
    a1 = bias1;
#pragma unroll 2
    for (int win = 0; win < kWinPerMat; ++win) {
      H8 wA = wpA[(size_t)win << 10];
      H8 wB = wpB[(size_t)win << 10];
      float4 pA = h0f0[2 * win], pB = h0f0[2 * win + 1];
      float4 qA = h0f1[2 * win], qB = h0f1[2 * win + 1];
      float4 rA = h1f0[2 * win], rB = h1f0[2 * win + 1];
      float4 sA = h1f1[2 * win], sB = h1f1[2 * win + 1];
      float2 f0 = __half22float2(wA.h[0]);
      float2 f1 = __half22float2(wA.h[1]);
      float2 f2 = __half22float2(wA.h[2]);
      float2 f3 = __half22float2(wA.h[3]);
      a0 = fmaf(f0.x, pA.x, a0); a0 = fmaf(f0.y, pA.y, a0);
      a0 = fmaf(f1.x, pA.z, a0); a0 = fmaf(f1.y, pA.w, a0);
      a0 = fmaf(f2.x, pB.x, a0); a0 = fmaf(f2.y, pB.y, a0);
      a0 = fmaf(f3.x, pB.z, a0); a0 = fmaf(f3.y, pB.w, a0);
      a1 = fmaf(f0.x, qA.x, a1); a1 = fmaf(f0.y, qA.y, a1);
      a1 = fmaf(f1.x, qA.z, a1); a1 = fmaf(f1.y, qA.w, a1);
      a1 = fmaf(f2.x, qB.x, a1); a1 = fmaf(f2.y, qB.y, a1);
      a1 = fmaf(f3.x, qB.z, a1); a1 = fmaf(f3.y, qB.w, a1);
      float2 g0 = __half22float2(wB.h[0]);
      float2 g1 = __half22float2(wB.h[1]);
      float2 g2 = __half22float2(wB.h[2]);
      float2 g3 = __half22float2(wB.h[3]);
      a0 = fmaf(g0.x, rA.x, a0); a0 = fmaf(g0.y, rA.y, a0);
      a0 = fmaf(g1.x, rA.z, a0); a0 = fmaf(g1.y, rA.w, a0);
      a0 = fmaf(g2.x, rB.x, a0); a0 = fmaf(g2.y, rB.y, a0);
      a0 = fmaf(g3.x, rB.z, a0); a0 = fmaf(g3.y, rB.w, a0);
      a1 = fmaf(g0.x, sA.x, a1); a1 = fmaf(g0.y, sA.y, a1);
      a1 = fmaf(g1.x, sA.z, a1); a1 = fmaf(g1.y, sA.w, a1);
      a1 = fmaf(g2.x, sB.x, a1); a1 = fmaf(g2.y, sB.y, a1);
      a1 = fmaf(g3.x, sB.z, a1); a1 = fmaf(g3.y, sB.w, a1);
    }
    g4[0][tid] = a0;
    g4[1][tid] = a1;
    __syncthreads();
    if (tid < 512) {
      float gi = fsig(g4[m][hr]);
      float gf = fsig(g4[m][hr + 256]);
      float gg = tanhf(g4[m][hr + 512]);
      float go = fsig(g4[m][hr + 768]);
      c1 = fmaf(gf, c1, gi * gg);
      float hn = go * tanhf(c1);
      h1s[m][hr] = hn;
      spred[m][hr] = hn * woutr;
    }
    __syncthreads();

    // ---- pred reduce (wave 0 -> m=0, wave 1 -> m=1), loss, feedback ----
    if (tid < 128) {
      int mr = tid >> 6, ln = tid & 63;
      float v = spred[mr][ln] + spred[mr][ln + 64] + spred[mr][ln + 128] +
                spred[mr][ln + 192];
#pragma unroll
      for (int off = 32; off > 0; off >>= 1) v += __shfl_down(v, off);
      if (ln == 0) {
        float pred = v + bo;
        float d = seq[(size_t)(b0 + mr) * kT + t] - pred;
        lacc = fmaf(d, d, lacc);
        xs[mr] = pred;
      }
    }
    __syncthreads();
  }

  if (tid < 128 && (tid & 63) == 0)
    atomicAdd(loss_out, lacc * (1.0f / (float)(kB * kT)));
}

// ---------------- fallback (round-1 structure, reads d_in directly) --------
__global__ __launch_bounds__(1024) void decoder_fallback(
    const float* __restrict__ seq, const float* __restrict__ z,
    const float* __restrict__ wih0, const float* __restrict__ bih0,
    const float* __restrict__ bhh0, const float* __restrict__ whh0,
    const float* __restrict__ wih1, const float* __restrict__ whh1,
    const float* __restrict__ bih1, const float* __restrict__ bhh1,
    const float* __restrict__ wout, const float* __restrict__ bout,
    float* __restrict__ loss_out) {
  __shared__ float h0s[kH], h1s[kH], g4[1024];
  __shared__ float xs_s;
  const int tid = threadIdx.x;
  const int b = blockIdx.x;
  float c0r = 0.f, c1r = 0.f;
  if (tid < kH) {
    float zv = z[b * kH + tid];
    h0s[tid] = zv; h1s[tid] = zv; c0r = zv; c1r = zv;
  }
  if (tid == 0) xs_s = 0.f;
  const float wih0_j = wih0[tid];
  const float bias0_j = bih0[tid] + bhh0[tid];
  const float bias1_j = bih1[tid] + bhh1[tid];
  const float wout_r = (tid < kH) ? wout[tid] : 0.f;
  const float bo = bout[0];
  float lacc = 0.f;
  __syncthreads();
  for (int t = 0; t < kT; ++t) {
    float a0 = fmaf(xs_s, wih0_j, bias0_j);
    for (int k = 0; k < kH; ++k) a0 = fmaf(whh0[tid * kH + k], h0s[k], a0);
    g4[tid] = a0;
    __syncthreads();
    if (tid < kH) {
      float ig = fsig(g4[tid]), fg = fsig(g4[tid + 256]);
      float gg = tanhf(g4[tid + 512]), og = fsig(g4[tid + 768]);
      c0r = fmaf(fg, c0r, ig * gg);
      h0s[tid] = og * tanhf(c0r);
    }
    __syncthreads();
    float a1 = bias1_j;
    for (int k = 0; k < kH; ++k) a1 = fmaf(wih1[tid * kH + k], h0s[k], a1);
    for (int k = 0; k < kH; ++k) a1 = fmaf(whh1[tid * kH + k], h1s[k], a1);
    g4[tid] = a1;
    __syncthreads();
    if (tid < kH) {
      float ig = fsig(g4[tid]), fg = fsig(g4[tid + 256]);
      float gg = tanhf(g4[tid + 512]), og = fsig(g4[tid + 768]);
      c1r = fmaf(fg, c1r, ig * gg);
      float h1 = og * tanhf(c1r);
      h1s[tid] = h1;
      g4[tid] = h1 * wout_r;
    }
    __syncthreads();
    if (tid < 64) {
      float v = g4[tid] + g4[tid + 64] + g4[tid + 128] + g4[tid + 192];
#pragma unroll
      for (int off = 32; off > 0; off >>= 1) v += __shfl_down(v, off);
      if (tid == 0) {
        float pred = v + bo;
        float d = seq[b * kT + t] - pred;
        lacc = fmaf(d, d, lacc);
        xs_s = pred;
      }
    }
    __syncthreads();
  }
  if (tid == 0) atomicAdd(loss_out, lacc * (1.0f / (float)(kB * kT)));
}

}  // namespace

extern "C" void kernel_launch(void* const* d_in, const int* in_sizes, int n_in,
                              void* d_out, int out_size, void* d_ws, size_t ws_size,
                              hipStream_t stream) {
  const float* seq = (const float*)d_in[0];
  const float* z = (const float*)d_in[1];
  const float* wih0 = (const float*)d_in[3];
  const float* whh0 = (const float*)d_in[4];
  const float* bih0 = (const float*)d_in[5];
  const float* bhh0 = (const float*)d_in[6];
  const float* wih1 = (const float*)d_in[7];
  const float* whh1 = (const float*)d_in[8];
  const float* bih1 = (const float*)d_in[9];
  const float* bhh1 = (const float*)d_in[10];
  const float* wout = (const float*)d_in[11];
  const float* bout = (const float*)d_in[12];
  float* out = (float*)d_out;

  hipMemsetAsync(out, 0, sizeof(float), stream);

  if (ws_size >= kWsNeeded) {
    H8* wpk = (H8*)d_ws;  // [3][32768] tiles: whh0, wih1, whh1
    pack_w<<<384, 256, 0, stream>>>(whh0, wih1, whh1, wpk);
    // 100 KB dummy dynamic LDS: ensures at most 1 block/CU so the 128 blocks
    // spread over 128 distinct CUs (no time-shared pairs).
    decoder_nb2<<<128, 1024, 100 * 1024, stream>>>(
        seq, z, wih0, bih0, bhh0, bih1, bhh1, wout, bout, wpk,
        wpk + kMatElems, wpk + 2 * kMatElems, out);
  } else {
    decoder_fallback<<<kB, 1024, 0, stream>>>(seq, z, wih0, bih0, bhh0, whh0,
                                              wih1, whh1, bih1, bhh1, wout, bout,
                                              out);
  }
}